// Round 1
// baseline (1244.157 us; speedup 1.0000x reference)
//
#include <hip/hip_runtime.h>
#include <math.h>

#define B_TOT 512
#define CQKV  256
#define CIN   128
#define HLEN  128

static constexpr float F_QR = 0.3f, F_KR = 0.3f, F_SV = 0.5f, F_SVE = 0.3f;
static constexpr float EPS = 1e-5f;

// ---------------------------------------------------------------------------
// Kernel 1: qkv[b][o][h] = sum_c w[o][c] * x[n][c][w][h],  b = n*64 + w
// One block per b. Thread (og,h) holds x-column h in 128 VGPRs; w reads are
// wave-uniform (og,r uniform) -> scalar loads. No LDS.
// ---------------------------------------------------------------------------
__global__ __launch_bounds__(256) void k_qkv(const float* __restrict__ x,
                                             const float* __restrict__ w,
                                             float* __restrict__ qkv) {
    int b = blockIdx.x;
    int n = b >> 6, wi = b & 63;
    int t = threadIdx.x;
    int h = t & 127;
    int og = t >> 7;                      // 0 or 1 (wave-uniform)
    const float* xb = x + ((size_t)n * CIN * 64 + (size_t)wi) * HLEN;
    float xcol[CIN];
#pragma unroll
    for (int c = 0; c < CIN; ++c) xcol[c] = xb[(size_t)c * 64 * HLEN + h];

    float* out = qkv + ((size_t)b * CQKV + og * 128) * HLEN + h;
    for (int r = 0; r < 128; ++r) {
        const float4* wr = (const float4*)(w + (size_t)(og * 128 + r) * CIN);
        float acc = 0.f;
#pragma unroll
        for (int c4 = 0; c4 < 32; ++c4) {
            float4 wv = wr[c4];
            acc = fmaf(wv.x, xcol[4 * c4 + 0], acc);
            acc = fmaf(wv.y, xcol[4 * c4 + 1], acc);
            acc = fmaf(wv.z, xcol[4 * c4 + 2], acc);
            acc = fmaf(wv.w, xcol[4 * c4 + 3], acc);
        }
        out[(size_t)r * HLEN] = acc;
    }
}

// ---------------------------------------------------------------------------
// Kernel 2: per-channel (256) stats over (b,h) of a (512,256,128) tensor.
// MODE 0: fused double-BN (g1,b1,g2,b2):  after BN1, mean=b1, var=g1^2*v/(v+eps)
//   => y2 = (x-mu)*scale + b2,  scale = g1*g2*r1*rsqrt(g1^2*v*r1^2 + eps)
// MODE 1: single BN (ga,ba).
// One block per channel; f64 accumulation (cancellation-safe).
// ---------------------------------------------------------------------------
template <int MODE>
__global__ __launch_bounds__(256) void k_chstats(const float* __restrict__ data,
                                                 const float* __restrict__ ga,
                                                 const float* __restrict__ ba,
                                                 const float* __restrict__ gb,
                                                 const float* __restrict__ bb,
                                                 float* __restrict__ scale,
                                                 float* __restrict__ shift) {
    int o = blockIdx.x;
    int t = threadIdx.x;
    double s = 0.0, ss = 0.0;
    for (int idx = t; idx < B_TOT * HLEN; idx += 256) {
        int b = idx >> 7, h = idx & 127;
        float v = data[((size_t)b * CQKV + o) * HLEN + h];
        s += v;
        ss += (double)v * v;
    }
    __shared__ double sh_s[256], sh_ss[256];
    sh_s[t] = s; sh_ss[t] = ss;
    __syncthreads();
    for (int off = 128; off > 0; off >>= 1) {
        if (t < off) { sh_s[t] += sh_s[t + off]; sh_ss[t] += sh_ss[t + off]; }
        __syncthreads();
    }
    if (t == 0) {
        double cnt  = (double)B_TOT * HLEN;
        double mean = sh_s[0] / cnt;
        double var  = sh_ss[0] / cnt - mean * mean;
        float sc, sf;
        if (MODE == 0) {
            float r1 = rsqrtf((float)var + EPS);
            float v2 = ga[o] * ga[o] * (float)var * r1 * r1;
            sc = ga[o] * gb[o] * r1 * rsqrtf(v2 + EPS);
            sf = bb[o] - (float)mean * sc;
        } else {
            sc = ga[o] * rsqrtf((float)var + EPS);
            sf = ba[o] - (float)mean * sc;
        }
        scale[o] = sc;
        shift[o] = sf;
    }
}

// ---------------------------------------------------------------------------
// Kernel 3: per (b,g) recompute qk / qr*0.3 / kr*0.3, accumulate sum+sumsq
// per head-channel (24 ch) via block reduction + double atomics.
// ---------------------------------------------------------------------------
__global__ __launch_bounds__(256) void k_scorestats(const float* __restrict__ qkv,
                                                    const float* __restrict__ scaleA,
                                                    const float* __restrict__ shiftA,
                                                    const float* __restrict__ rel,
                                                    double* __restrict__ accS) {
    __shared__ float qs[8][128], ks[8][128], rs[16][256];
    __shared__ float red[256];
    int blk = blockIdx.x, b = blk >> 3, g = blk & 7;
    int t = threadIdx.x;
    for (int idx = t; idx < 16 * 128; idx += 256) {
        int cc = idx >> 7, h = idx & 127;
        int o = g * 32 + cc;
        float v = qkv[((size_t)b * CQKV + o) * HLEN + h] * scaleA[o] + shiftA[o];
        if (cc < 8) qs[cc][h] = v; else ks[cc - 8][h] = v;
    }
    for (int idx = t; idx < 16 * 255; idx += 256) {
        int r = idx / 255, c = idx - r * 255;
        rs[r][c] = rel[r * 255 + c];
    }
    __syncthreads();

    int i = t >> 1, j0 = (t & 1) * 64;
    float qreg[8];
#pragma unroll
    for (int c = 0; c < 8; ++c) qreg[c] = qs[c][i];
    float v6[6] = {0, 0, 0, 0, 0, 0};   // s_qk ss_qk s_qr ss_qr s_kr ss_kr
    for (int jj = 0; jj < 64; ++jj) {
        int j = j0 + jj;
        float qk = 0, qr = 0, kr = 0;
#pragma unroll
        for (int c = 0; c < 8; ++c) {
            float kv = ks[c][j];
            qk = fmaf(qreg[c], kv, qk);
            qr = fmaf(qreg[c], rs[c][i - j + 127], qr);
            kr = fmaf(kv, rs[8 + c][j - i + 127], kr);
        }
        qr *= F_QR; kr *= F_KR;
        v6[0] += qk; v6[1] += qk * qk;
        v6[2] += qr; v6[3] += qr * qr;
        v6[4] += kr; v6[5] += kr * kr;
    }
    int ch[6] = {g, g, 8 + g, 8 + g, 16 + g, 16 + g};
#pragma unroll
    for (int q = 0; q < 6; ++q) {
        red[t] = v6[q];
        __syncthreads();
        for (int off = 128; off > 0; off >>= 1) {
            if (t < off) red[t] += red[t + off];
            __syncthreads();
        }
        if (t == 0) atomicAdd(&accS[ch[q] * 2 + (q & 1)], (double)red[0]);
        __syncthreads();
    }
}

__global__ void k_sfin(const double* __restrict__ accS,
                       const float* __restrict__ gs, const float* __restrict__ bs,
                       float* __restrict__ scaleS, float* __restrict__ shiftS) {
    int c = threadIdx.x;
    if (c < 24) {
        double cnt  = 512.0 * 128.0 * 128.0;
        double mean = accS[c * 2] / cnt;
        double var  = accS[c * 2 + 1] / cnt - mean * mean;
        float sc = gs[c] * rsqrtf((float)var + EPS);
        scaleS[c] = sc;
        shiftS[c] = bs[c] - (float)mean * sc;
    }
}

// ---------------------------------------------------------------------------
// Kernel 5: per (b,g): recompute scores, BN affine + group sum, row softmax,
// then sv = 0.5*P@v^T and sve = 0.3*sum_j P[i][j]*rel[16+c][i-j+127].
// S tile padded [128][129] (kills stride-128 bank conflicts).
// ---------------------------------------------------------------------------
__global__ __launch_bounds__(256) void k_attn(const float* __restrict__ qkv,
                                              const float* __restrict__ scaleA,
                                              const float* __restrict__ shiftA,
                                              const float* __restrict__ rel,
                                              const float* __restrict__ scaleS,
                                              const float* __restrict__ shiftS,
                                              float* __restrict__ so) {
    __shared__ float S[128][129];
    __shared__ float qs[8][128], ks[8][128], vs[16][128];
    __shared__ float rs[32][256];
    int blk = blockIdx.x, b = blk >> 3, g = blk & 7;
    int t = threadIdx.x;
    for (int idx = t; idx < 32 * 128; idx += 256) {
        int cc = idx >> 7, h = idx & 127;
        int o = g * 32 + cc;
        float v = qkv[((size_t)b * CQKV + o) * HLEN + h] * scaleA[o] + shiftA[o];
        if (cc < 8)       qs[cc][h] = v;
        else if (cc < 16) ks[cc - 8][h] = v;
        else              vs[cc - 16][h] = v;
    }
    for (int idx = t; idx < 32 * 255; idx += 256) {
        int r = idx / 255, c = idx - r * 255;
        rs[r][c] = rel[r * 255 + c];
    }
    __syncthreads();

    float scA = scaleS[g], scB = scaleS[8 + g], scC = scaleS[16 + g];
    float shsum = shiftS[g] + shiftS[8 + g] + shiftS[16 + g];

    int i = t >> 1, j0 = (t & 1) * 64;
    float qreg[8];
#pragma unroll
    for (int c = 0; c < 8; ++c) qreg[c] = qs[c][i];
    float rowmax = -1e30f;
    for (int jj = 0; jj < 64; ++jj) {
        int j = j0 + jj;
        float qk = 0, qr = 0, kr = 0;
#pragma unroll
        for (int c = 0; c < 8; ++c) {
            float kv = ks[c][j];
            qk = fmaf(qreg[c], kv, qk);
            qr = fmaf(qreg[c], rs[c][i - j + 127], qr);
            kr = fmaf(kv, rs[8 + c][j - i + 127], kr);
        }
        float sv = qk * scA + (qr * F_QR) * scB + (kr * F_KR) * scC + shsum;
        S[i][j] = sv;
        rowmax = fmaxf(rowmax, sv);
    }
    rowmax = fmaxf(rowmax, __shfl_xor(rowmax, 1));
    float rsum = 0.f;
    for (int jj = 0; jj < 64; ++jj) {
        int j = j0 + jj;
        float e = __expf(S[i][j] - rowmax);
        S[i][j] = e;
        rsum += e;
    }
    rsum += __shfl_xor(rsum, 1);
    float rn = 1.f / rsum;
    for (int jj = 0; jj < 64; ++jj) S[i][j0 + jj] *= rn;
    __syncthreads();

    // PV: half 0 -> sv (c 0..15 x i), half 1 -> sve. Thread: i in {ig, ig+64}.
    int half = t >> 7, l = t & 127, cg = l >> 6, ig = l & 63;
    int c0 = cg * 8;
    float a0[8] = {0, 0, 0, 0, 0, 0, 0, 0};
    float a1[8] = {0, 0, 0, 0, 0, 0, 0, 0};
    if (half == 0) {
        for (int j = 0; j < 128; ++j) {
            float p0 = S[ig][j], p1 = S[ig + 64][j];
#pragma unroll
            for (int c = 0; c < 8; ++c) {
                float vv = vs[c0 + c][j];
                a0[c] = fmaf(p0, vv, a0[c]);
                a1[c] = fmaf(p1, vv, a1[c]);
            }
        }
#pragma unroll
        for (int c = 0; c < 8; ++c) {
            int o = g * 32 + (c0 + c) * 2;
            so[((size_t)b * CQKV + o) * HLEN + ig]      = a0[c] * F_SV;
            so[((size_t)b * CQKV + o) * HLEN + ig + 64] = a1[c] * F_SV;
        }
    } else {
        for (int j = 0; j < 128; ++j) {
            float p0 = S[ig][j], p1 = S[ig + 64][j];
#pragma unroll
            for (int c = 0; c < 8; ++c) {
                float r0 = rs[16 + c0 + c][ig - j + 127];
                float r1 = rs[16 + c0 + c][ig + 64 - j + 127];
                a0[c] = fmaf(p0, r0, a0[c]);
                a1[c] = fmaf(p1, r1, a1[c]);
            }
        }
#pragma unroll
        for (int c = 0; c < 8; ++c) {
            int o = g * 32 + (c0 + c) * 2 + 1;
            so[((size_t)b * CQKV + o) * HLEN + ig]      = a0[c] * F_SVE;
            so[((size_t)b * CQKV + o) * HLEN + ig + 64] = a1[c] * F_SVE;
        }
    }
}

// ---------------------------------------------------------------------------
// Kernel 7: final affine + pair-sum + transpose: out[n][oc][w][h]
// ---------------------------------------------------------------------------
__global__ __launch_bounds__(256) void k_out(const float* __restrict__ so,
                                             const float* __restrict__ scale,
                                             const float* __restrict__ shift,
                                             float* __restrict__ out) {
    int b = blockIdx.x, n = b >> 6, wi = b & 63;
    int t = threadIdx.x, h = t & 127, half = t >> 7;
    for (int oc = half * 64; oc < half * 64 + 64; ++oc) {
        float v0 = so[((size_t)b * CQKV + 2 * oc) * HLEN + h] * scale[2 * oc] + shift[2 * oc];
        float v1 = so[((size_t)b * CQKV + 2 * oc + 1) * HLEN + h] * scale[2 * oc + 1] + shift[2 * oc + 1];
        out[(((size_t)n * 128 + oc) * 64 + wi) * HLEN + h] = v0 + v1;
    }
}

extern "C" void kernel_launch(void* const* d_in, const int* in_sizes, int n_in,
                              void* d_out, int out_size, void* d_ws, size_t ws_size,
                              hipStream_t stream) {
    const float* x   = (const float*)d_in[0];
    const float* w   = (const float*)d_in[1];
    const float* g1  = (const float*)d_in[2];
    const float* b1  = (const float*)d_in[3];
    const float* g2  = (const float*)d_in[4];
    const float* b2  = (const float*)d_in[5];
    const float* gs  = (const float*)d_in[6];
    const float* bs  = (const float*)d_in[7];
    const float* go  = (const float*)d_in[8];
    const float* bo  = (const float*)d_in[9];
    const float* rel = (const float*)d_in[10];
    float* out = (float*)d_out;

    float*  qkv    = (float*)d_ws;                 // 16,777,216 f
    float*  so     = qkv + (size_t)16777216;       // 16,777,216 f
    double* accS   = (double*)(so + (size_t)16777216);  // 48 d (8B aligned)
    float*  scaleA = (float*)(accS + 48);
    float*  shiftA = scaleA + 256;
    float*  scaleS = shiftA + 256;                 // 24
    float*  shiftS = scaleS + 24;
    float*  scaleF = shiftS + 24;                  // 256
    float*  shiftF = scaleF + 256;

    hipMemsetAsync(accS, 0, 48 * sizeof(double), stream);

    k_qkv<<<512, 256, 0, stream>>>(x, w, qkv);
    k_chstats<0><<<256, 256, 0, stream>>>(qkv, g1, b1, g2, b2, scaleA, shiftA);
    k_scorestats<<<4096, 256, 0, stream>>>(qkv, scaleA, shiftA, rel, accS);
    k_sfin<<<1, 32, 0, stream>>>(accS, gs, bs, scaleS, shiftS);
    k_attn<<<4096, 256, 0, stream>>>(qkv, scaleA, shiftA, rel, scaleS, shiftS, so);
    k_chstats<1><<<256, 256, 0, stream>>>(so, go, bo, nullptr, nullptr, scaleF, shiftF);
    k_out<<<512, 256, 0, stream>>>(so, scaleF, shiftF, out);
}

// Round 2
// 968.493 us; speedup vs baseline: 1.2846x; 1.2846x over previous
//
#include <hip/hip_runtime.h>
#include <math.h>

#define B_TOT 512
#define CQKV  256
#define CIN   128
#define HLEN  128

static constexpr float F_QR = 0.3f, F_KR = 0.3f, F_SV = 0.5f, F_SVE = 0.3f;
static constexpr float EPS = 1e-5f;

__device__ __forceinline__ unsigned short f2bf(float f) {
    unsigned u = __float_as_uint(f);
    unsigned r = u + 0x7fffu + ((u >> 16) & 1u);
    return (unsigned short)(r >> 16);
}
__device__ __forceinline__ float bfl(unsigned u) { return __uint_as_float(u << 16); }
__device__ __forceinline__ float bfh(unsigned u) { return __uint_as_float(u & 0xffff0000u); }

// ---------------------------------------------------------------------------
// Kernel 1: qkv[b][o][h] = sum_c w[o][c] * x[n][c][w][h],  b = n*64 + w
// ---------------------------------------------------------------------------
__global__ __launch_bounds__(256) void k_qkv(const float* __restrict__ x,
                                             const float* __restrict__ w,
                                             float* __restrict__ qkv) {
    int b = blockIdx.x;
    int n = b >> 6, wi = b & 63;
    int t = threadIdx.x;
    int h = t & 127;
    int og = t >> 7;
    const float* xb = x + ((size_t)n * CIN * 64 + (size_t)wi) * HLEN;
    float xcol[CIN];
#pragma unroll
    for (int c = 0; c < CIN; ++c) xcol[c] = xb[(size_t)c * 64 * HLEN + h];

    float* out = qkv + ((size_t)b * CQKV + og * 128) * HLEN + h;
    for (int r = 0; r < 128; ++r) {
        const float4* wr = (const float4*)(w + (size_t)(og * 128 + r) * CIN);
        float acc = 0.f;
#pragma unroll
        for (int c4 = 0; c4 < 32; ++c4) {
            float4 wv = wr[c4];
            acc = fmaf(wv.x, xcol[4 * c4 + 0], acc);
            acc = fmaf(wv.y, xcol[4 * c4 + 1], acc);
            acc = fmaf(wv.z, xcol[4 * c4 + 2], acc);
            acc = fmaf(wv.w, xcol[4 * c4 + 3], acc);
        }
        out[(size_t)r * HLEN] = acc;
    }
}

// ---------------------------------------------------------------------------
// Kernel 2: per-channel stats -> fused affine (scale, shift)
// ---------------------------------------------------------------------------
template <int MODE>
__global__ __launch_bounds__(256) void k_chstats(const float* __restrict__ data,
                                                 const float* __restrict__ ga,
                                                 const float* __restrict__ ba,
                                                 const float* __restrict__ gb,
                                                 const float* __restrict__ bb,
                                                 float* __restrict__ scale,
                                                 float* __restrict__ shift) {
    int o = blockIdx.x;
    int t = threadIdx.x;
    double s = 0.0, ss = 0.0;
    for (int idx = t; idx < B_TOT * HLEN; idx += 256) {
        int b = idx >> 7, h = idx & 127;
        float v = data[((size_t)b * CQKV + o) * HLEN + h];
        s += v;
        ss += (double)v * v;
    }
    __shared__ double sh_s[256], sh_ss[256];
    sh_s[t] = s; sh_ss[t] = ss;
    __syncthreads();
    for (int off = 128; off > 0; off >>= 1) {
        if (t < off) { sh_s[t] += sh_s[t + off]; sh_ss[t] += sh_ss[t + off]; }
        __syncthreads();
    }
    if (t == 0) {
        double cnt  = (double)B_TOT * HLEN;
        double mean = sh_s[0] / cnt;
        double var  = sh_ss[0] / cnt - mean * mean;
        float sc, sf;
        if (MODE == 0) {
            float r1 = rsqrtf((float)var + EPS);
            float v2 = ga[o] * ga[o] * (float)var * r1 * r1;
            sc = ga[o] * gb[o] * r1 * rsqrtf(v2 + EPS);
            sf = bb[o] - (float)mean * sc;
        } else {
            sc = ga[o] * rsqrtf((float)var + EPS);
            sf = ba[o] - (float)mean * sc;
        }
        scale[o] = sc;
        shift[o] = sf;
    }
}

// ---------------------------------------------------------------------------
// Tables for analytic score stats.
//   Rq[c][i]  = sum_{d=i}^{i+127} rq[c][d]          (rq = rel rows 0..7)
//   Rk[c][j]  = sum_{d=j}^{j+127} rk[c][d]          (rk = rel rows 8..15)
//   TqT[i*64+p] = sum_{d=i}^{i+127} rq[c][d]*rq[c'][d],  p=(c<<3)|c'
//   TkT likewise for rel rows 8..15.
// ---------------------------------------------------------------------------
__global__ __launch_bounds__(128) void k_tables(const float* __restrict__ rel,
                                                float* __restrict__ Rq, float* __restrict__ Rk,
                                                float* __restrict__ TqT, float* __restrict__ TkT) {
    int bid = blockIdx.x;      // 0..127
    int i = threadIdx.x;       // 0..127
    int p = bid & 63;
    int c = p >> 3, c2 = p & 7;
    const float* ra = (bid < 64) ? (rel + c * 255)  : (rel + (8 + c) * 255);
    const float* rb = (bid < 64) ? (rel + c2 * 255) : (rel + (8 + c2) * 255);
    float tacc = 0.f;
    for (int kk = 0; kk < 128; ++kk) tacc = fmaf(ra[i + kk], rb[i + kk], tacc);
    if (bid < 64) TqT[i * 64 + p] = tacc; else TkT[i * 64 + p] = tacc;
    if (c2 == 0) {
        float racc = 0.f;
        for (int kk = 0; kk < 128; ++kk) racc += ra[i + kk];
        if (bid < 64) Rq[c * 128 + i] = racc; else Rk[c * 128 + i] = racc;
    }
}

// ---------------------------------------------------------------------------
// Analytic score stats per (b,g): Gram matrices instead of 128x128 recompute.
// ---------------------------------------------------------------------------
__global__ __launch_bounds__(64) void k_gram(const float* __restrict__ qkv,
                                             const float* __restrict__ scaleA,
                                             const float* __restrict__ shiftA,
                                             const float* __restrict__ Rq,
                                             const float* __restrict__ Rk,
                                             const float* __restrict__ TqT,
                                             const float* __restrict__ TkT,
                                             double* __restrict__ accS) {
    __shared__ float qs[8][132], ks[8][132];
    int blk = blockIdx.x, b = blk >> 3, g = blk & 7;
    int t = threadIdx.x;
    for (int idx = t; idx < 2048; idx += 64) {
        int cc = idx >> 7, h = idx & 127, o = g * 32 + cc;
        float v = qkv[((size_t)b * CQKV + o) * HLEN + h] * scaleA[o] + shiftA[o];
        if (cc < 8) qs[cc][h] = v; else ks[cc - 8][h] = v;
    }
    __syncthreads();
    int c = t >> 3, c2 = t & 7;
    float gq = 0, gk = 0, tq = 0, tk = 0;
    for (int i = 0; i < 128; ++i) {
        float a = qs[c][i] * qs[c2][i];
        float e = ks[c][i] * ks[c2][i];
        gq += a; gk += e;
        tq = fmaf(a, TqT[i * 64 + t], tq);
        tk = fmaf(e, TkT[i * 64 + t], tk);
    }
    float ssqk = gq * gk;
    float sqr = 0, skr = 0;
    float sq8[8], sk8[8];
#pragma unroll
    for (int c3 = 0; c3 < 8; ++c3) {
        float q0 = qs[c3][t], q1 = qs[c3][t + 64];
        float k0 = ks[c3][t], k1 = ks[c3][t + 64];
        sq8[c3] = q0 + q1; sk8[c3] = k0 + k1;
        sqr = fmaf(q0, Rq[c3 * 128 + t], sqr);
        sqr = fmaf(q1, Rq[c3 * 128 + t + 64], sqr);
        skr = fmaf(k0, Rk[c3 * 128 + t], skr);
        skr = fmaf(k1, Rk[c3 * 128 + t + 64], skr);
    }
#pragma unroll
    for (int off = 1; off < 64; off <<= 1) {
        ssqk += __shfl_xor(ssqk, off);
        tq   += __shfl_xor(tq, off);
        tk   += __shfl_xor(tk, off);
        sqr  += __shfl_xor(sqr, off);
        skr  += __shfl_xor(skr, off);
#pragma unroll
        for (int c3 = 0; c3 < 8; ++c3) {
            sq8[c3] += __shfl_xor(sq8[c3], off);
            sk8[c3] += __shfl_xor(sk8[c3], off);
        }
    }
    if (t == 0) {
        float sqk = 0;
#pragma unroll
        for (int c3 = 0; c3 < 8; ++c3) sqk += sq8[c3] * sk8[c3];
        atomicAdd(&accS[g * 2 + 0], (double)sqk);
        atomicAdd(&accS[g * 2 + 1], (double)ssqk);
        atomicAdd(&accS[(8 + g) * 2 + 0], (double)(F_QR * sqr));
        atomicAdd(&accS[(8 + g) * 2 + 1], (double)(F_QR * F_QR * tq));
        atomicAdd(&accS[(16 + g) * 2 + 0], (double)(F_KR * skr));
        atomicAdd(&accS[(16 + g) * 2 + 1], (double)(F_KR * F_KR * tk));
    }
}

__global__ void k_sfin(const double* __restrict__ accS,
                       const float* __restrict__ gs, const float* __restrict__ bs,
                       float* __restrict__ scaleS, float* __restrict__ shiftS) {
    int c = threadIdx.x;
    if (c < 24) {
        double cnt  = 512.0 * 128.0 * 128.0;
        double mean = accS[c * 2] / cnt;
        double var  = accS[c * 2 + 1] / cnt - mean * mean;
        float sc = gs[c] * rsqrtf((float)var + EPS);
        scaleS[c] = sc;
        shiftS[c] = bs[c] - (float)mean * sc;
    }
}

// ---------------------------------------------------------------------------
// Attention: scores in registers (p[64] per thread, 2 threads per row),
// transposed K/V in LDS (b128 broadcasts), bf16-packed rel tables (one b128
// per Toeplitz gather). ~36.8 KB LDS.
// ---------------------------------------------------------------------------
__global__ __launch_bounds__(256) void k_attn(const float* __restrict__ qkv,
                                              const float* __restrict__ scaleA,
                                              const float* __restrict__ shiftA,
                                              const float* __restrict__ rel,
                                              const float* __restrict__ scaleS,
                                              const float* __restrict__ shiftS,
                                              float* __restrict__ so) {
    __shared__ float qs[8][128];
    __shared__ float kT[128][12];
    __shared__ float vT[128][20];
    __shared__ unsigned short rqT[255][8];
    __shared__ unsigned short rkT[255][8];
    __shared__ unsigned short rvA[255][8];
    __shared__ unsigned short rvB[255][8];
    int blk = blockIdx.x, b = blk >> 3, g = blk & 7;
    int t = threadIdx.x;
    for (int idx = t; idx < 32 * 128; idx += 256) {
        int cc = idx >> 7, h = idx & 127, o = g * 32 + cc;
        float v = qkv[((size_t)b * CQKV + o) * HLEN + h] * scaleA[o] + shiftA[o];
        if (cc < 8)       qs[cc][h] = v;
        else if (cc < 16) kT[h][cc - 8] = v;
        else              vT[h][cc - 16] = v;
    }
    for (int idx = t; idx < 32 * 255; idx += 256) {
        int r = idx / 255, d = idx - r * 255;
        unsigned short us = f2bf(rel[r * 255 + d]);
        if (r < 8)       rqT[d][r] = us;
        else if (r < 16) rkT[d][r - 8] = us;
        else if (r < 24) rvA[d][r - 16] = us;
        else             rvB[d][r - 24] = us;
    }
    __syncthreads();

    float cA = scaleS[g], cB = F_QR * scaleS[8 + g], cC = F_KR * scaleS[16 + g];
    float shsum = shiftS[g] + shiftS[8 + g] + shiftS[16 + g];

    int i = t >> 1, j0 = (t & 1) << 6;
    float qreg[8];
#pragma unroll
    for (int c = 0; c < 8; ++c) qreg[c] = qs[c][i];

    float p[64];
    float rowmax = -1e30f;
#pragma unroll
    for (int jj = 0; jj < 64; ++jj) {
        int j = j0 + jj;
        float4 ka = *(const float4*)&kT[j][0];
        float4 kb = *(const float4*)&kT[j][4];
        uint4 rq = *(const uint4*)&rqT[i - j + 127][0];
        uint4 rk = *(const uint4*)&rkT[j - i + 127][0];
        float qk = fmaf(qreg[0], ka.x, fmaf(qreg[1], ka.y, fmaf(qreg[2], ka.z, fmaf(qreg[3], ka.w,
                   fmaf(qreg[4], kb.x, fmaf(qreg[5], kb.y, fmaf(qreg[6], kb.z, qreg[7] * kb.w)))))));
        float qr = fmaf(qreg[0], bfl(rq.x), fmaf(qreg[1], bfh(rq.x), fmaf(qreg[2], bfl(rq.y), fmaf(qreg[3], bfh(rq.y),
                   fmaf(qreg[4], bfl(rq.z), fmaf(qreg[5], bfh(rq.z), fmaf(qreg[6], bfl(rq.w), qreg[7] * bfh(rq.w))))))));
        float kr = fmaf(ka.x, bfl(rk.x), fmaf(ka.y, bfh(rk.x), fmaf(ka.z, bfl(rk.y), fmaf(ka.w, bfh(rk.y),
                   fmaf(kb.x, bfl(rk.z), fmaf(kb.y, bfh(rk.z), fmaf(kb.z, bfl(rk.w), kb.w * bfh(rk.w))))))));
        float s = fmaf(qk, cA, fmaf(qr, cB, fmaf(kr, cC, shsum)));
        p[jj] = s;
        rowmax = fmaxf(rowmax, s);
    }
    rowmax = fmaxf(rowmax, __shfl_xor(rowmax, 1));
    float rsum = 0.f;
#pragma unroll
    for (int jj = 0; jj < 64; ++jj) {
        float e = __expf(p[jj] - rowmax);
        p[jj] = e;
        rsum += e;
    }
    rsum += __shfl_xor(rsum, 1);
    float rn = 1.f / rsum;

    // ---- sv = P @ V^T ----
    float a0[16];
#pragma unroll
    for (int c = 0; c < 16; ++c) a0[c] = 0.f;
#pragma unroll
    for (int jj = 0; jj < 64; ++jj) {
        int j = j0 + jj;
        float pj = p[jj];
        float4 v0 = *(const float4*)&vT[j][0];
        float4 v1 = *(const float4*)&vT[j][4];
        float4 v2 = *(const float4*)&vT[j][8];
        float4 v3 = *(const float4*)&vT[j][12];
        a0[0]  = fmaf(pj, v0.x, a0[0]);  a0[1]  = fmaf(pj, v0.y, a0[1]);
        a0[2]  = fmaf(pj, v0.z, a0[2]);  a0[3]  = fmaf(pj, v0.w, a0[3]);
        a0[4]  = fmaf(pj, v1.x, a0[4]);  a0[5]  = fmaf(pj, v1.y, a0[5]);
        a0[6]  = fmaf(pj, v1.z, a0[6]);  a0[7]  = fmaf(pj, v1.w, a0[7]);
        a0[8]  = fmaf(pj, v2.x, a0[8]);  a0[9]  = fmaf(pj, v2.y, a0[9]);
        a0[10] = fmaf(pj, v2.z, a0[10]); a0[11] = fmaf(pj, v2.w, a0[11]);
        a0[12] = fmaf(pj, v3.x, a0[12]); a0[13] = fmaf(pj, v3.y, a0[13]);
        a0[14] = fmaf(pj, v3.z, a0[14]); a0[15] = fmaf(pj, v3.w, a0[15]);
    }
#pragma unroll
    for (int c = 0; c < 16; ++c) a0[c] += __shfl_xor(a0[c], 1);
    {
        int cbase = (t & 1) * 8;
        float scv = F_SV * rn;
        float* sop = so + ((size_t)b * CQKV + g * 32) * HLEN + i;
#pragma unroll
        for (int c8 = 0; c8 < 8; ++c8) {
            int c = cbase + c8;
            sop[(size_t)(2 * c) * HLEN] = a0[c] * scv;
        }
    }

    // ---- sve = P (*) v_emb (Toeplitz) ----
    float a1[16];
#pragma unroll
    for (int c = 0; c < 16; ++c) a1[c] = 0.f;
#pragma unroll
    for (int jj = 0; jj < 64; ++jj) {
        int j = j0 + jj;
        int d = i - j + 127;
        float pj = p[jj];
        uint4 ra = *(const uint4*)&rvA[d][0];
        uint4 rb = *(const uint4*)&rvB[d][0];
        a1[0]  = fmaf(pj, bfl(ra.x), a1[0]);  a1[1]  = fmaf(pj, bfh(ra.x), a1[1]);
        a1[2]  = fmaf(pj, bfl(ra.y), a1[2]);  a1[3]  = fmaf(pj, bfh(ra.y), a1[3]);
        a1[4]  = fmaf(pj, bfl(ra.z), a1[4]);  a1[5]  = fmaf(pj, bfh(ra.z), a1[5]);
        a1[6]  = fmaf(pj, bfl(ra.w), a1[6]);  a1[7]  = fmaf(pj, bfh(ra.w), a1[7]);
        a1[8]  = fmaf(pj, bfl(rb.x), a1[8]);  a1[9]  = fmaf(pj, bfh(rb.x), a1[9]);
        a1[10] = fmaf(pj, bfl(rb.y), a1[10]); a1[11] = fmaf(pj, bfh(rb.y), a1[11]);
        a1[12] = fmaf(pj, bfl(rb.z), a1[12]); a1[13] = fmaf(pj, bfh(rb.z), a1[13]);
        a1[14] = fmaf(pj, bfl(rb.w), a1[14]); a1[15] = fmaf(pj, bfh(rb.w), a1[15]);
    }
#pragma unroll
    for (int c = 0; c < 16; ++c) a1[c] += __shfl_xor(a1[c], 1);
    {
        int cbase = (t & 1) * 8;
        float sce = F_SVE * rn;
        float* sop = so + ((size_t)b * CQKV + g * 32) * HLEN + i;
#pragma unroll
        for (int c8 = 0; c8 < 8; ++c8) {
            int c = cbase + c8;
            sop[(size_t)(2 * c + 1) * HLEN] = a1[c] * sce;
        }
    }
}

// ---------------------------------------------------------------------------
// Final affine + pair-sum + transpose
// ---------------------------------------------------------------------------
__global__ __launch_bounds__(256) void k_out(const float* __restrict__ so,
                                             const float* __restrict__ scale,
                                             const float* __restrict__ shift,
                                             float* __restrict__ out) {
    int b = blockIdx.x, n = b >> 6, wi = b & 63;
    int t = threadIdx.x, h = t & 127, half = t >> 7;
    for (int oc = half * 64; oc < half * 64 + 64; ++oc) {
        float v0 = so[((size_t)b * CQKV + 2 * oc) * HLEN + h] * scale[2 * oc] + shift[2 * oc];
        float v1 = so[((size_t)b * CQKV + 2 * oc + 1) * HLEN + h] * scale[2 * oc + 1] + shift[2 * oc + 1];
        out[(((size_t)n * 128 + oc) * 64 + wi) * HLEN + h] = v0 + v1;
    }
}

extern "C" void kernel_launch(void* const* d_in, const int* in_sizes, int n_in,
                              void* d_out, int out_size, void* d_ws, size_t ws_size,
                              hipStream_t stream) {
    const float* x   = (const float*)d_in[0];
    const float* w   = (const float*)d_in[1];
    const float* g1  = (const float*)d_in[2];
    const float* b1  = (const float*)d_in[3];
    const float* g2  = (const float*)d_in[4];
    const float* b2  = (const float*)d_in[5];
    const float* gs  = (const float*)d_in[6];
    const float* bs  = (const float*)d_in[7];
    const float* go  = (const float*)d_in[8];
    const float* bo  = (const float*)d_in[9];
    const float* rel = (const float*)d_in[10];
    float* out = (float*)d_out;

    float*  qkv    = (float*)d_ws;                      // 16,777,216 f
    float*  so     = qkv + (size_t)16777216;            // 16,777,216 f
    double* accS   = (double*)(so + (size_t)16777216);  // 48 d
    float*  scaleA = (float*)(accS + 48);
    float*  shiftA = scaleA + 256;
    float*  scaleS = shiftA + 256;                      // 24
    float*  shiftS = scaleS + 24;
    float*  scaleF = shiftS + 24;                       // 256
    float*  shiftF = scaleF + 256;
    float*  Rq     = shiftF + 256;                      // 1024
    float*  Rk     = Rq + 1024;                         // 1024
    float*  TqT    = Rk + 1024;                         // 8192
    float*  TkT    = TqT + 8192;                        // 8192

    hipMemsetAsync(accS, 0, 48 * sizeof(double), stream);

    k_qkv<<<512, 256, 0, stream>>>(x, w, qkv);
    k_tables<<<128, 128, 0, stream>>>(rel, Rq, Rk, TqT, TkT);
    k_chstats<0><<<256, 256, 0, stream>>>(qkv, g1, b1, g2, b2, scaleA, shiftA);
    k_gram<<<4096, 64, 0, stream>>>(qkv, scaleA, shiftA, Rq, Rk, TqT, TkT, accS);
    k_sfin<<<1, 32, 0, stream>>>(accS, gs, bs, scaleS, shiftS);
    k_attn<<<4096, 256, 0, stream>>>(qkv, scaleA, shiftA, rel, scaleS, shiftS, so);
    k_chstats<1><<<256, 256, 0, stream>>>(so, go, bo, nullptr, nullptr, scaleF, shiftF);
    k_out<<<512, 256, 0, stream>>>(so, scaleF, shiftF, out);
}

// Round 3
// 821.193 us; speedup vs baseline: 1.5151x; 1.1794x over previous
//
#include <hip/hip_runtime.h>
#include <math.h>

#define B_TOT 512
#define CQKV  256
#define CIN   128
#define HLEN  128

static constexpr float F_QR = 0.3f, F_KR = 0.3f, F_SV = 0.5f, F_SVE = 0.3f;
static constexpr float EPS = 1e-5f;

__device__ __forceinline__ unsigned short f2bf(float f) {
    unsigned u = __float_as_uint(f);
    unsigned r = u + 0x7fffu + ((u >> 16) & 1u);
    return (unsigned short)(r >> 16);
}
__device__ __forceinline__ float bfl(unsigned u) { return __uint_as_float(u << 16); }
__device__ __forceinline__ float bfh(unsigned u) { return __uint_as_float(u & 0xffff0000u); }

// ---------------------------------------------------------------------------
// Kernel 1: qkv[b][o][h] = sum_c w[o][c] * x[n][c][w][h],  b = n*64 + w
// 8 independent accumulator chains per thread (dep distance 16 cyc > 4 cyc
// FMA latency) -> issue-rate-bound instead of chain-latency-bound.
// ---------------------------------------------------------------------------
__global__ __launch_bounds__(256) void k_qkv(const float* __restrict__ x,
                                             const float* __restrict__ w,
                                             float* __restrict__ qkv) {
    int b = blockIdx.x;
    int n = b >> 6, wi = b & 63;
    int t = threadIdx.x;
    int h = t & 127;
    int og = t >> 7;
    const float* xb = x + ((size_t)n * CIN * 64 + (size_t)wi) * HLEN;
    float xcol[CIN];
#pragma unroll
    for (int c = 0; c < CIN; ++c) xcol[c] = xb[(size_t)c * 64 * HLEN + h];

    float* out = qkv + ((size_t)b * CQKV + og * 128) * HLEN + h;
    const float* wbase = w + (size_t)og * 128 * CIN;
    for (int r8 = 0; r8 < 128; r8 += 8) {
        float acc[8] = {0, 0, 0, 0, 0, 0, 0, 0};
#pragma unroll
        for (int c4 = 0; c4 < 32; ++c4) {
#pragma unroll
            for (int rr = 0; rr < 8; ++rr) {
                const float4 wv = *(const float4*)(wbase + (size_t)(r8 + rr) * CIN + c4 * 4);
                acc[rr] = fmaf(wv.x, xcol[4 * c4 + 0], acc[rr]);
                acc[rr] = fmaf(wv.y, xcol[4 * c4 + 1], acc[rr]);
                acc[rr] = fmaf(wv.z, xcol[4 * c4 + 2], acc[rr]);
                acc[rr] = fmaf(wv.w, xcol[4 * c4 + 3], acc[rr]);
            }
        }
#pragma unroll
        for (int rr = 0; rr < 8; ++rr) out[(size_t)(r8 + rr) * HLEN] = acc[rr];
    }
}

// ---------------------------------------------------------------------------
// Kernel 2: per-channel stats -> fused affine (scale, shift)
// ---------------------------------------------------------------------------
template <int MODE>
__global__ __launch_bounds__(256) void k_chstats(const float* __restrict__ data,
                                                 const float* __restrict__ ga,
                                                 const float* __restrict__ ba,
                                                 const float* __restrict__ gb,
                                                 const float* __restrict__ bb,
                                                 float* __restrict__ scale,
                                                 float* __restrict__ shift) {
    int o = blockIdx.x;
    int t = threadIdx.x;
    double s = 0.0, ss = 0.0;
    for (int idx = t; idx < B_TOT * HLEN; idx += 256) {
        int b = idx >> 7, h = idx & 127;
        float v = data[((size_t)b * CQKV + o) * HLEN + h];
        s += v;
        ss += (double)v * v;
    }
    __shared__ double sh_s[256], sh_ss[256];
    sh_s[t] = s; sh_ss[t] = ss;
    __syncthreads();
    for (int off = 128; off > 0; off >>= 1) {
        if (t < off) { sh_s[t] += sh_s[t + off]; sh_ss[t] += sh_ss[t + off]; }
        __syncthreads();
    }
    if (t == 0) {
        double cnt  = (double)B_TOT * HLEN;
        double mean = sh_s[0] / cnt;
        double var  = sh_ss[0] / cnt - mean * mean;
        float sc, sf;
        if (MODE == 0) {
            float r1 = rsqrtf((float)var + EPS);
            float v2 = ga[o] * ga[o] * (float)var * r1 * r1;
            sc = ga[o] * gb[o] * r1 * rsqrtf(v2 + EPS);
            sf = bb[o] - (float)mean * sc;
        } else {
            sc = ga[o] * rsqrtf((float)var + EPS);
            sf = ba[o] - (float)mean * sc;
        }
        scale[o] = sc;
        shift[o] = sf;
    }
}

// ---------------------------------------------------------------------------
// Tables for analytic score stats.
// ---------------------------------------------------------------------------
__global__ __launch_bounds__(128) void k_tables(const float* __restrict__ rel,
                                                float* __restrict__ Rq, float* __restrict__ Rk,
                                                float* __restrict__ TqT, float* __restrict__ TkT) {
    int bid = blockIdx.x;      // 0..127
    int i = threadIdx.x;       // 0..127
    int p = bid & 63;
    int c = p >> 3, c2 = p & 7;
    const float* ra = (bid < 64) ? (rel + c * 255)  : (rel + (8 + c) * 255);
    const float* rb = (bid < 64) ? (rel + c2 * 255) : (rel + (8 + c2) * 255);
    float tacc = 0.f;
    for (int kk = 0; kk < 128; ++kk) tacc = fmaf(ra[i + kk], rb[i + kk], tacc);
    if (bid < 64) TqT[i * 64 + p] = tacc; else TkT[i * 64 + p] = tacc;
    if (c2 == 0) {
        float racc = 0.f;
        for (int kk = 0; kk < 128; ++kk) racc += ra[i + kk];
        if (bid < 64) Rq[c * 128 + i] = racc; else Rk[c * 128 + i] = racc;
    }
}

// ---------------------------------------------------------------------------
// Analytic score stats per (b,g): Gram matrices instead of 128x128 recompute.
// ---------------------------------------------------------------------------
__global__ __launch_bounds__(64) void k_gram(const float* __restrict__ qkv,
                                             const float* __restrict__ scaleA,
                                             const float* __restrict__ shiftA,
                                             const float* __restrict__ Rq,
                                             const float* __restrict__ Rk,
                                             const float* __restrict__ TqT,
                                             const float* __restrict__ TkT,
                                             double* __restrict__ accS) {
    __shared__ float qs[8][132], ks[8][132];
    int blk = blockIdx.x, b = blk >> 3, g = blk & 7;
    int t = threadIdx.x;
    for (int idx = t; idx < 2048; idx += 64) {
        int cc = idx >> 7, h = idx & 127, o = g * 32 + cc;
        float v = qkv[((size_t)b * CQKV + o) * HLEN + h] * scaleA[o] + shiftA[o];
        if (cc < 8) qs[cc][h] = v; else ks[cc - 8][h] = v;
    }
    __syncthreads();
    int c = t >> 3, c2 = t & 7;
    float gq = 0, gk = 0, tq = 0, tk = 0;
    for (int i = 0; i < 128; ++i) {
        float a = qs[c][i] * qs[c2][i];
        float e = ks[c][i] * ks[c2][i];
        gq += a; gk += e;
        tq = fmaf(a, TqT[i * 64 + t], tq);
        tk = fmaf(e, TkT[i * 64 + t], tk);
    }
    float ssqk = gq * gk;
    float sqr = 0, skr = 0;
    float sq8[8], sk8[8];
#pragma unroll
    for (int c3 = 0; c3 < 8; ++c3) {
        float q0 = qs[c3][t], q1 = qs[c3][t + 64];
        float k0 = ks[c3][t], k1 = ks[c3][t + 64];
        sq8[c3] = q0 + q1; sk8[c3] = k0 + k1;
        sqr = fmaf(q0, Rq[c3 * 128 + t], sqr);
        sqr = fmaf(q1, Rq[c3 * 128 + t + 64], sqr);
        skr = fmaf(k0, Rk[c3 * 128 + t], skr);
        skr = fmaf(k1, Rk[c3 * 128 + t + 64], skr);
    }
#pragma unroll
    for (int off = 1; off < 64; off <<= 1) {
        ssqk += __shfl_xor(ssqk, off);
        tq   += __shfl_xor(tq, off);
        tk   += __shfl_xor(tk, off);
        sqr  += __shfl_xor(sqr, off);
        skr  += __shfl_xor(skr, off);
#pragma unroll
        for (int c3 = 0; c3 < 8; ++c3) {
            sq8[c3] += __shfl_xor(sq8[c3], off);
            sk8[c3] += __shfl_xor(sk8[c3], off);
        }
    }
    if (t == 0) {
        float sqk = 0;
#pragma unroll
        for (int c3 = 0; c3 < 8; ++c3) sqk += sq8[c3] * sk8[c3];
        atomicAdd(&accS[g * 2 + 0], (double)sqk);
        atomicAdd(&accS[g * 2 + 1], (double)ssqk);
        atomicAdd(&accS[(8 + g) * 2 + 0], (double)(F_QR * sqr));
        atomicAdd(&accS[(8 + g) * 2 + 1], (double)(F_QR * F_QR * tq));
        atomicAdd(&accS[(16 + g) * 2 + 0], (double)(F_KR * skr));
        atomicAdd(&accS[(16 + g) * 2 + 1], (double)(F_KR * F_KR * tk));
    }
}

__global__ void k_sfin(const double* __restrict__ accS,
                       const float* __restrict__ gs, const float* __restrict__ bs,
                       float* __restrict__ scaleS, float* __restrict__ shiftS) {
    int c = threadIdx.x;
    if (c < 24) {
        double cnt  = 512.0 * 128.0 * 128.0;
        double mean = accS[c * 2] / cnt;
        double var  = accS[c * 2 + 1] / cnt - mean * mean;
        float sc = gs[c] * rsqrtf((float)var + EPS);
        scaleS[c] = sc;
        shiftS[c] = bs[c] - (float)mean * sc;
    }
}

// ---------------------------------------------------------------------------
// Attention: scores in registers, transposed K/V in LDS, bf16 rel tables.
// ---------------------------------------------------------------------------
__global__ __launch_bounds__(256) void k_attn(const float* __restrict__ qkv,
                                              const float* __restrict__ scaleA,
                                              const float* __restrict__ shiftA,
                                              const float* __restrict__ rel,
                                              const float* __restrict__ scaleS,
                                              const float* __restrict__ shiftS,
                                              float* __restrict__ so) {
    __shared__ float qs[8][128];
    __shared__ float kT[128][12];
    __shared__ float vT[128][20];
    __shared__ unsigned short rqT[255][8];
    __shared__ unsigned short rkT[255][8];
    __shared__ unsigned short rvA[255][8];
    __shared__ unsigned short rvB[255][8];
    int blk = blockIdx.x, b = blk >> 3, g = blk & 7;
    int t = threadIdx.x;
    for (int idx = t; idx < 32 * 128; idx += 256) {
        int cc = idx >> 7, h = idx & 127, o = g * 32 + cc;
        float v = qkv[((size_t)b * CQKV + o) * HLEN + h] * scaleA[o] + shiftA[o];
        if (cc < 8)       qs[cc][h] = v;
        else if (cc < 16) kT[h][cc - 8] = v;
        else              vT[h][cc - 16] = v;
    }
    for (int idx = t; idx < 32 * 255; idx += 256) {
        int r = idx / 255, d = idx - r * 255;
        unsigned short us = f2bf(rel[r * 255 + d]);
        if (r < 8)       rqT[d][r] = us;
        else if (r < 16) rkT[d][r - 8] = us;
        else if (r < 24) rvA[d][r - 16] = us;
        else             rvB[d][r - 24] = us;
    }
    __syncthreads();

    float cA = scaleS[g], cB = F_QR * scaleS[8 + g], cC = F_KR * scaleS[16 + g];
    float shsum = shiftS[g] + shiftS[8 + g] + shiftS[16 + g];

    int i = t >> 1, j0 = (t & 1) << 6;
    float qreg[8];
#pragma unroll
    for (int c = 0; c < 8; ++c) qreg[c] = qs[c][i];

    float p[64];
    float rowmax = -1e30f;
#pragma unroll
    for (int jj = 0; jj < 64; ++jj) {
        int j = j0 + jj;
        float4 ka = *(const float4*)&kT[j][0];
        float4 kb = *(const float4*)&kT[j][4];
        uint4 rq = *(const uint4*)&rqT[i - j + 127][0];
        uint4 rk = *(const uint4*)&rkT[j - i + 127][0];
        float qk = fmaf(qreg[0], ka.x, fmaf(qreg[1], ka.y, fmaf(qreg[2], ka.z, fmaf(qreg[3], ka.w,
                   fmaf(qreg[4], kb.x, fmaf(qreg[5], kb.y, fmaf(qreg[6], kb.z, qreg[7] * kb.w)))))));
        float qr = fmaf(qreg[0], bfl(rq.x), fmaf(qreg[1], bfh(rq.x), fmaf(qreg[2], bfl(rq.y), fmaf(qreg[3], bfh(rq.y),
                   fmaf(qreg[4], bfl(rq.z), fmaf(qreg[5], bfh(rq.z), fmaf(qreg[6], bfl(rq.w), qreg[7] * bfh(rq.w))))))));
        float kr = fmaf(ka.x, bfl(rk.x), fmaf(ka.y, bfh(rk.x), fmaf(ka.z, bfl(rk.y), fmaf(ka.w, bfh(rk.y),
                   fmaf(kb.x, bfl(rk.z), fmaf(kb.y, bfh(rk.z), fmaf(kb.z, bfl(rk.w), kb.w * bfh(rk.w))))))));
        float s = fmaf(qk, cA, fmaf(qr, cB, fmaf(kr, cC, shsum)));
        p[jj] = s;
        rowmax = fmaxf(rowmax, s);
    }
    rowmax = fmaxf(rowmax, __shfl_xor(rowmax, 1));
    float rsum = 0.f;
#pragma unroll
    for (int jj = 0; jj < 64; ++jj) {
        float e = __expf(p[jj] - rowmax);
        p[jj] = e;
        rsum += e;
    }
    rsum += __shfl_xor(rsum, 1);
    float rn = 1.f / rsum;

    // ---- sv = P @ V^T ----
    float a0[16];
#pragma unroll
    for (int c = 0; c < 16; ++c) a0[c] = 0.f;
#pragma unroll
    for (int jj = 0; jj < 64; ++jj) {
        int j = j0 + jj;
        float pj = p[jj];
        float4 v0 = *(const float4*)&vT[j][0];
        float4 v1 = *(const float4*)&vT[j][4];
        float4 v2 = *(const float4*)&vT[j][8];
        float4 v3 = *(const float4*)&vT[j][12];
        a0[0]  = fmaf(pj, v0.x, a0[0]);  a0[1]  = fmaf(pj, v0.y, a0[1]);
        a0[2]  = fmaf(pj, v0.z, a0[2]);  a0[3]  = fmaf(pj, v0.w, a0[3]);
        a0[4]  = fmaf(pj, v1.x, a0[4]);  a0[5]  = fmaf(pj, v1.y, a0[5]);
        a0[6]  = fmaf(pj, v1.z, a0[6]);  a0[7]  = fmaf(pj, v1.w, a0[7]);
        a0[8]  = fmaf(pj, v2.x, a0[8]);  a0[9]  = fmaf(pj, v2.y, a0[9]);
        a0[10] = fmaf(pj, v2.z, a0[10]); a0[11] = fmaf(pj, v2.w, a0[11]);
        a0[12] = fmaf(pj, v3.x, a0[12]); a0[13] = fmaf(pj, v3.y, a0[13]);
        a0[14] = fmaf(pj, v3.z, a0[14]); a0[15] = fmaf(pj, v3.w, a0[15]);
    }
#pragma unroll
    for (int c = 0; c < 16; ++c) a0[c] += __shfl_xor(a0[c], 1);
    {
        int cbase = (t & 1) * 8;
        float scv = F_SV * rn;
        float* sop = so + ((size_t)b * CQKV + g * 32) * HLEN + i;
#pragma unroll
        for (int c8 = 0; c8 < 8; ++c8) {
            int c = cbase + c8;
            sop[(size_t)(2 * c) * HLEN] = a0[c] * scv;
        }
    }

    // ---- sve = P (*) v_emb (Toeplitz) ----
    float a1[16];
#pragma unroll
    for (int c = 0; c < 16; ++c) a1[c] = 0.f;
#pragma unroll
    for (int jj = 0; jj < 64; ++jj) {
        int j = j0 + jj;
        int d = i - j + 127;
        float pj = p[jj];
        uint4 ra = *(const uint4*)&rvA[d][0];
        uint4 rb = *(const uint4*)&rvB[d][0];
        a1[0]  = fmaf(pj, bfl(ra.x), a1[0]);  a1[1]  = fmaf(pj, bfh(ra.x), a1[1]);
        a1[2]  = fmaf(pj, bfl(ra.y), a1[2]);  a1[3]  = fmaf(pj, bfh(ra.y), a1[3]);
        a1[4]  = fmaf(pj, bfl(ra.z), a1[4]);  a1[5]  = fmaf(pj, bfh(ra.z), a1[5]);
        a1[6]  = fmaf(pj, bfl(ra.w), a1[6]);  a1[7]  = fmaf(pj, bfh(ra.w), a1[7]);
        a1[8]  = fmaf(pj, bfl(rb.x), a1[8]);  a1[9]  = fmaf(pj, bfh(rb.x), a1[9]);
        a1[10] = fmaf(pj, bfl(rb.y), a1[10]); a1[11] = fmaf(pj, bfh(rb.y), a1[11]);
        a1[12] = fmaf(pj, bfl(rb.z), a1[12]); a1[13] = fmaf(pj, bfh(rb.z), a1[13]);
        a1[14] = fmaf(pj, bfl(rb.w), a1[14]); a1[15] = fmaf(pj, bfh(rb.w), a1[15]);
    }
#pragma unroll
    for (int c = 0; c < 16; ++c) a1[c] += __shfl_xor(a1[c], 1);
    {
        int cbase = (t & 1) * 8;
        float sce = F_SVE * rn;
        float* sop = so + ((size_t)b * CQKV + g * 32) * HLEN + i;
#pragma unroll
        for (int c8 = 0; c8 < 8; ++c8) {
            int c = cbase + c8;
            sop[(size_t)(2 * c + 1) * HLEN] = a1[c] * sce;
        }
    }
}

// ---------------------------------------------------------------------------
// Final affine + pair-sum + transpose
// ---------------------------------------------------------------------------
__global__ __launch_bounds__(256) void k_out(const float* __restrict__ so,
                                             const float* __restrict__ scale,
                                             const float* __restrict__ shift,
                                             float* __restrict__ out) {
    int b = blockIdx.x, n = b >> 6, wi = b & 63;
    int t = threadIdx.x, h = t & 127, half = t >> 7;
    for (int oc = half * 64; oc < half * 64 + 64; ++oc) {
        float v0 = so[((size_t)b * CQKV + 2 * oc) * HLEN + h] * scale[2 * oc] + shift[2 * oc];
        float v1 = so[((size_t)b * CQKV + 2 * oc + 1) * HLEN + h] * scale[2 * oc + 1] + shift[2 * oc + 1];
        out[(((size_t)n * 128 + oc) * 64 + wi) * HLEN + h] = v0 + v1;
    }
}

extern "C" void kernel_launch(void* const* d_in, const int* in_sizes, int n_in,
                              void* d_out, int out_size, void* d_ws, size_t ws_size,
                              hipStream_t stream) {
    const float* x   = (const float*)d_in[0];
    const float* w   = (const float*)d_in[1];
    const float* g1  = (const float*)d_in[2];
    const float* b1  = (const float*)d_in[3];
    const float* g2  = (const float*)d_in[4];
    const float* b2  = (const float*)d_in[5];
    const float* gs  = (const float*)d_in[6];
    const float* bs  = (const float*)d_in[7];
    const float* go  = (const float*)d_in[8];
    const float* bo  = (const float*)d_in[9];
    const float* rel = (const float*)d_in[10];
    float* out = (float*)d_out;

    float*  qkv    = (float*)d_ws;                      // 16,777,216 f
    float*  so     = qkv + (size_t)16777216;            // 16,777,216 f
    double* accS   = (double*)(so + (size_t)16777216);  // 48 d
    float*  scaleA = (float*)(accS + 48);
    float*  shiftA = scaleA + 256;
    float*  scaleS = shiftA + 256;                      // 24
    float*  shiftS = scaleS + 24;
    float*  scaleF = shiftS + 24;                       // 256
    float*  shiftF = scaleF + 256;
    float*  Rq     = shiftF + 256;                      // 1024
    float*  Rk     = Rq + 1024;                         // 1024
    float*  TqT    = Rk + 1024;                         // 8192
    float*  TkT    = TqT + 8192;                        // 8192

    hipMemsetAsync(accS, 0, 48 * sizeof(double), stream);

    k_qkv<<<512, 256, 0, stream>>>(x, w, qkv);
    k_tables<<<128, 128, 0, stream>>>(rel, Rq, Rk, TqT, TkT);
    k_chstats<0><<<256, 256, 0, stream>>>(qkv, g1, b1, g2, b2, scaleA, shiftA);
    k_gram<<<4096, 64, 0, stream>>>(qkv, scaleA, shiftA, Rq, Rk, TqT, TkT, accS);
    k_sfin<<<1, 32, 0, stream>>>(accS, gs, bs, scaleS, shiftS);
    k_attn<<<4096, 256, 0, stream>>>(qkv, scaleA, shiftA, rel, scaleS, shiftS, so);
    k_chstats<1><<<256, 256, 0, stream>>>(so, go, bo, nullptr, nullptr, scaleF, shiftF);
    k_out<<<512, 256, 0, stream>>>(so, scaleF, shiftF, out);
}